// Round 1
// baseline (156.338 us; speedup 1.0000x reference)
//
#include <hip/hip_runtime.h>

// ConvSpatialPropagationNet_71949292143069
//
// Analysis: in the reference, `nws = einsum('bchw,c->bhw', gate_wb * dp[:,None], sum_w)[:,1:-1,1:-1]`
// multiplies every gate channel by the SAME (h,w) of the padded depth (dp is broadcast over c,
// not shifted per channel). Hence nws = gate_sum * d pointwise, and the body reduces to
//   d <- (1-gs)*raw + gs*d   (then mask-blend with raw, mask in {0,1})
// with d0 = raw. raw is the exact fixpoint and the initial value, so d == raw == blur_depth
// for all 24 steps (fp drift ~3e-6 << 2e-2 threshold). The kernel is a pure copy.

__global__ void __launch_bounds__(256)
copy_blur_kernel(const float4* __restrict__ src, float4* __restrict__ dst, int n4) {
    int i = blockIdx.x * blockDim.x + threadIdx.x;
    if (i < n4) {
        dst[i] = src[i];
    }
}

__global__ void __launch_bounds__(64)
copy_tail_kernel(const float* __restrict__ src, float* __restrict__ dst, int start, int n) {
    int i = start + blockIdx.x * blockDim.x + threadIdx.x;
    if (i < n) {
        dst[i] = src[i];
    }
}

extern "C" void kernel_launch(void* const* d_in, const int* in_sizes, int n_in,
                              void* d_out, int out_size, void* d_ws, size_t ws_size,
                              hipStream_t stream) {
    // Inputs (setup_inputs order): guidance, blur_depth, sparse_depth, sum_w
    const float* blur = (const float*)d_in[1];
    float* out = (float*)d_out;

    int n = out_size;          // B*1*H*W = 3,424,256 (divisible by 4)
    int n4 = n >> 2;
    int block = 256;
    int grid = (n4 + block - 1) / block;

    copy_blur_kernel<<<grid, block, 0, stream>>>(
        (const float4*)blur, (float4*)out, n4);

    int tail_start = n4 << 2;
    int tail = n - tail_start;
    if (tail > 0) {
        copy_tail_kernel<<<1, 64, 0, stream>>>(blur, out, tail_start, n);
    }
}